// Round 23
// baseline (134.488 us; speedup 1.0000x reference)
//
#include <hip/hip_runtime.h>

// CRF loss: A=8, S=200, B=64, T=32. scores (A,S,B,T,T) f32, targets (A,S,B) i32,
// mask (S,B) bool, a_mask (A,B) bool -- bool width (u8 vs i32) runtime-detected.
// R23 = R22 (barrier-free producer/consumer flag ring) with the consumer loop
// made RUNTIME-BOUNDED. Diagnosis: R9/R10/R22 all failed with absmax=496.0 and
// all had compile-time-unrollable consumer step sequences; all passing kernels
// used runtime loop bounds. The hipcc unrolled wlds store->load chain is
// miscompiled; runtime bound prevents the unroll. Flag poll is per-tile inside
// the loop (consumer starts step j as soon as tile j lands).
constexpr int A_ = 8, S_ = 200, B_ = 64, T_ = 32;
constexpr int START_TAG = 30, END_TAG = 31;
constexpr int NW = 8;                      // producer waves
constexpr int NT = (NW + 1) * 64;          // 576 threads; wave 8 = consumer
constexpr int NSLOT = 16;                  // ring slots (4KB each, 64KB)
#define LOG2E 1.44269504088896340736f
#define LN2   0.69314718055994530942f

#if __has_builtin(__builtin_amdgcn_exp2f)
#define EXP2F(x) __builtin_amdgcn_exp2f(x)
#else
#define EXP2F(x) __expf((x) * LN2)
#endif

__device__ __forceinline__ int load_flag(const void* p, bool u8, int idx) {
    return u8 ? (int)((const unsigned char*)p)[idx] : ((const int*)p)[idx];
}

__global__ __launch_bounds__(NT)
void crf_loss_kernel(const float* __restrict__ scores,
                     const int* __restrict__ targets,
                     const void* __restrict__ mask,
                     const void* __restrict__ amask,
                     float* __restrict__ out)
{
    const int chain = blockIdx.x;          // 0..511
    const int a = chain >> 6;
    const int b = chain & (B_ - 1);
    const int tid = threadIdx.x;
    const int wv = tid >> 6;               // 0..7 producers, 8 consumer
    const int lane = tid & 63;
    const int t = lane & 31;
    const int fbase = (lane >> 5) << 4;    // 0 or 16

    // bool width detect: mask row 0 is all-true. int view: 1 -> int32, 0x01010101 -> uint8
    const bool bool_u8 = (((const int*)mask)[0] != 1);
    if (!load_flag(amask, bool_u8, a * B_ + b)) return;   // uniform block exit

    __shared__ __align__(16) float ebuf[NSLOT][T_ * T_];  // 16 x 4KB exp-tile ring
    __shared__ int flags[NSLOT];                          // monotonic tile index
    __shared__ int consv;                                 // consumer progress
    __shared__ int tg_lds[S_];
    __shared__ float wlds[T_];                            // w vector (consumer)
    __shared__ float gfin[NW];                            // per-wave gold sums

    // ---- init ring control ----
    if (tid < NSLOT) flags[tid] = 0;
    if (tid == 0) consv = 0;

    // ---- first false mask index L (prefix mask) ----
    int L = S_;
    for (int base = 0; base < S_; base += 64) {
        int i = base + lane;
        int mv = (i < S_) ? load_flag(mask, bool_u8, i * B_ + b) : 1;
        unsigned long long bal = __ballot(mv == 0);
        if (bal != 0ull && L == S_) L = base + (int)__builtin_ctzll(bal);
    }

    for (int i = tid; i < S_; i += NT)
        tg_lds[i] = targets[((size_t)a * S_ + i) * B_ + b];
    __syncthreads();                        // ring control + tg_lds ready

    const size_t s_stride = (size_t)B_ * T_ * T_;         // 65536 floats per step
    const float* cb = scores + ((size_t)a * S_ * B_ + b) * (T_ * T_);

    float wcur = 0.0f, C2 = 0.0f, tg0 = 0.0f;
    if (wv == NW) {                         // consumer init
        wcur = EXP2F(cb[START_TAG * T_ + t] * LOG2E);
        if (lane < 32) wlds[lane] = wcur;
        tg0 = cb[tg_lds[0]];
    }
    float tgacc = 0.0f;                     // per-producer gold sum (uniform)

#define E4(DST, SRC) do {                                                \
        DST.x = EXP2F(SRC.x * LOG2E); DST.y = EXP2F(SRC.y * LOG2E);      \
        DST.z = EXP2F(SRC.z * LOG2E); DST.w = EXP2F(SRC.w * LOG2E);      \
    } while (0)

#define RENORM do {                                                      \
        float m_ = wcur;                                                 \
        m_ = fmaxf(m_, __shfl_xor(m_, 1));                               \
        m_ = fmaxf(m_, __shfl_xor(m_, 2));                               \
        m_ = fmaxf(m_, __shfl_xor(m_, 4));                               \
        m_ = fmaxf(m_, __shfl_xor(m_, 8));                               \
        m_ = fmaxf(m_, __shfl_xor(m_, 16));                              \
        int eb_ = (__float_as_int(m_) >> 23) & 0xff;                     \
        C2 += (float)(eb_ - 127);                                        \
        float sc2_ = __int_as_float((254 - eb_) << 23);                  \
        wcur *= sc2_;                                                    \
        if (lane < 32) wlds[lane] = wcur;                                \
    } while (0)

#define TLOAD(Q0, Q1, Q2, Q3, GR, SC) do {                               \
        const int s_ = (SC);                                             \
        if (s_ < L) {                                                    \
            const float*  p_  = cb + (size_t)s_ * s_stride;              \
            const float4* p4_ = (const float4*)p_;                       \
            Q0 = p4_[lane];       Q1 = p4_[64 + lane];                   \
            Q2 = p4_[128 + lane]; Q3 = p4_[192 + lane];                  \
            GR = p_[tg_lds[s_]];                                         \
        }                                                                \
    } while (0)

    // Producer: wait slot free, exp-write tile SS, drain DS, publish flag.
#define PUT(Q0, Q1, Q2, Q3, GQ, SS) do {                                 \
        const int s_ = (SS);                                             \
        while (*(volatile int*)&consv < s_ - NSLOT)                      \
            __builtin_amdgcn_s_sleep(2);                                 \
        asm volatile("" ::: "memory");                                   \
        float4 e0, e1, e2, e3;                                           \
        E4(e0, Q0); E4(e1, Q1); E4(e2, Q2); E4(e3, Q3);                  \
        float4* ebw = (float4*)&ebuf[(s_ - 1) & (NSLOT - 1)][0];         \
        ebw[lane] = e0; ebw[64 + lane] = e1;                             \
        ebw[128 + lane] = e2; ebw[192 + lane] = e3;                      \
        tgacc += GQ;                                                     \
        asm volatile("s_waitcnt lgkmcnt(0)" ::: "memory");               \
        if (lane == 0)                                                   \
            *(volatile int*)&flags[(s_ - 1) & (NSLOT - 1)] = s_;         \
    } while (0)

    // One consumer recursion step from ring slot SL (R20's verbatim body).
#define STEPC(SL) do {                                                   \
        const float* eb = &ebuf[SL][0];                                  \
        float4 wa_ = *(const float4*)&wlds[fbase];                       \
        float4 wb_ = *(const float4*)&wlds[fbase + 4];                   \
        float4 wc_ = *(const float4*)&wlds[fbase + 8];                   \
        float4 wd_ = *(const float4*)&wlds[fbase + 12];                  \
        float e_[16];                                                    \
        _Pragma("unroll")                                                \
        for (int i = 0; i < 16; ++i)                                     \
            e_[i] = eb[((fbase + i) << 5) | t];                          \
        float s0_ = fmaf(e_[3], wa_.w, fmaf(e_[2], wa_.z,                \
                    fmaf(e_[1], wa_.y, e_[0] * wa_.x)));                 \
        float s1_ = fmaf(e_[7], wb_.w, fmaf(e_[6], wb_.z,                \
                    fmaf(e_[5], wb_.y, e_[4] * wb_.x)));                 \
        float s2_ = fmaf(e_[11], wc_.w, fmaf(e_[10], wc_.z,              \
                    fmaf(e_[9], wc_.y, e_[8] * wc_.x)));                 \
        float s3_ = fmaf(e_[15], wd_.w, fmaf(e_[14], wd_.z,              \
                    fmaf(e_[13], wd_.y, e_[12] * wd_.x)));               \
        float s_ = (s0_ + s1_) + (s2_ + s3_);                            \
        s_ += __shfl_xor(s_, 32);                                        \
        wcur = s_;                                                       \
        if (lane < 32) wlds[lane] = s_;                                  \
    } while (0)

    if (wv < NW) {
        // ---- producer: depth-2 named-set prefetch (proven idiom), no barriers ----
        float4 a0, a1, a2, a3, b0, b1, b2, b3;
        float ga = 0.0f, gb = 0.0f;
        TLOAD(a0, a1, a2, a3, ga, 1 + wv);
        TLOAD(b0, b1, b2, b3, gb, 1 + wv + NW);
        for (int s = 1 + wv; s < L; s += 2 * NW) {
            PUT(a0, a1, a2, a3, ga, s);
            TLOAD(a0, a1, a2, a3, ga, s + 2 * NW);
            if (s + NW < L) {
                PUT(b0, b1, b2, b3, gb, s + NW);
                TLOAD(b0, b1, b2, b3, gb, s + 3 * NW);
            }
        }
    } else {
        // ---- consumer: groups of <=8 steps, RUNTIME loop bound (no unroll:
        // the unrolled wlds store->load chain is miscompiled -- R9/R10/R22),
        // per-tile flag poll inside the loop, renorm once per group ----
        int s = 1;
        while (s < L) {
            const int g = min(8, L - s);              // runtime (L is runtime)
            const int base = (s - 1) & (NSLOT - 1);   // aligned: 0 or 8
            for (int j = 0; j < g; ++j) {
                while (*(volatile int*)&flags[base + j] != s + j)
                    __builtin_amdgcn_s_sleep(1);
                asm volatile("" ::: "memory");
                STEPC(base + j);
            }
            RENORM;                                   // once per group (R20 cadence)
            s += g;
            if (lane == 0) *(volatile int*)&consv = s - 1;
        }
    }

    // ---- gold-path handoff + epilogue ----
    if (wv < NW && lane == 0) gfin[wv] = tgacc;
    __syncthreads();

    if (wv == NW) {
        float tg = tg0;
#pragma unroll
        for (int w = 0; w < NW; ++w) tg += gfin[w];
        float wend = __shfl(wcur, END_TAG);
        float logZ = __logf(wend) + C2 * LN2;
        if (lane == 0)
            atomicAdd(out, (logZ - tg) * (1.0f / (float)B_));
    }
}

extern "C" void kernel_launch(void* const* d_in, const int* in_sizes, int n_in,
                              void* d_out, int out_size, void* d_ws, size_t ws_size,
                              hipStream_t stream) {
    const float* scores = (const float*)d_in[0];
    const int* targets  = (const int*)d_in[1];
    const void* mask    = d_in[2];
    const void* amask   = d_in[3];
    float* out = (float*)d_out;

    hipMemsetAsync(out, 0, sizeof(float), stream);
    crf_loss_kernel<<<dim3(A_ * B_), dim3(NT), 0, stream>>>(
        scores, targets, mask, amask, out);
}

// Round 24
// 100.094 us; speedup vs baseline: 1.3436x; 1.3436x over previous
//
#include <hip/hip_runtime.h>

// CRF loss: A=8, S=200, B=64, T=32. scores (A,S,B,T,T) f32, targets (A,S,B) i32,
// mask (S,B) bool, a_mask (A,B) bool -- bool width (u8 vs i32) runtime-detected.
// R24: MEET-IN-THE-MIDDLE. logZ = w0^T M1..M_{L-1} e_END splits exactly:
// F = w0^T M1..M_nf (forward recursion, wave 0) and G = M_{nf+1}..M_{L-1} e_END
// (backward recursion v_j = M_j v_{j+1}, wave 4) run CONCURRENTLY; combine as
// logZ = log(F.G) + (C2f+C2b)ln2. Serial chain halves: ~199 -> ~100 steps.
// Skeleton = R20 champion (73us): lgkm-only barrier, named A/B producer reg
// sets (2-phase cover), dual-duty consumer waves, RUNTIME j-loops (constant-
// trip consumer loops are miscompiled: R9/R10/R22 all absmax=496), renorm per
// phase, producer-side gold path. Backward tiles stored with full-word XOR
// swizzle (word = f*32 + (t^f), both write and read) -> conflict-free reads.
constexpr int A_ = 8, S_ = 200, B_ = 64, T_ = 32;
constexpr int START_TAG = 30, END_TAG = 31;
constexpr int NW = 8;                      // waves: 0-3 fwd producers, 4-7 bwd
#define LOG2E 1.44269504088896340736f
#define LN2   0.69314718055994530942f

#if __has_builtin(__builtin_amdgcn_exp2f)
#define EXP2F(x) __builtin_amdgcn_exp2f(x)
#else
#define EXP2F(x) __expf((x) * LN2)
#endif

__device__ __forceinline__ int load_flag(const void* p, bool u8, int idx) {
    return u8 ? (int)((const unsigned char*)p)[idx] : ((const int*)p)[idx];
}

// LDS-writes-visible barrier WITHOUT vmcnt drain (proven R7/R12/R20).
#define LGKM_BARRIER do {                                                \
        asm volatile("s_waitcnt lgkmcnt(0)" ::: "memory");               \
        __builtin_amdgcn_s_barrier();                                    \
        asm volatile("" ::: "memory");                                   \
    } while (0)

__global__ __launch_bounds__(NW * 64)
void crf_loss_kernel(const float* __restrict__ scores,
                     const int* __restrict__ targets,
                     const void* __restrict__ mask,
                     const void* __restrict__ amask,
                     float* __restrict__ out)
{
    const int chain = blockIdx.x;          // 0..511
    const int a = chain >> 6;
    const int b = chain & (B_ - 1);
    const int tid = threadIdx.x;
    const int wv = tid >> 6;               // 0..7
    const int lane = tid & 63;
    const int t = lane & 31;               // fwd: to-tag; bwd: from-tag (f)
    const int fbase = (lane >> 5) << 4;    // 0 or 16 (reduction half)

    // bool width detect: mask row 0 is all-true. int view: 1 -> int32, 0x01010101 -> uint8
    const bool bool_u8 = (((const int*)mask)[0] != 1);
    if (!load_flag(amask, bool_u8, a * B_ + b)) return;   // uniform block exit

    __shared__ __align__(16) float ebuf[2][NW][T_ * T_];  // 2 x 8 x 4KB exp-tiles
    __shared__ int tg_lds[S_];
    __shared__ float wldsF[T_];                           // forward F (wave 0)
    __shared__ float wldsG[T_];                           // backward G (wave 4)
    __shared__ float gfin[NW];                            // per-wave gold sums
    __shared__ float c2b_lds;                             // wave 4's C2

    // ---- first false mask index L (prefix mask) ----
    int L = S_;
    for (int base = 0; base < S_; base += 64) {
        int i = base + lane;
        int mv = (i < S_) ? load_flag(mask, bool_u8, i * B_ + b) : 1;
        unsigned long long bal = __ballot(mv == 0);
        if (bal != 0ull && L == S_) L = base + (int)__builtin_ctzll(bal);
    }

    for (int i = tid; i < S_; i += NW * 64)
        tg_lds[i] = targets[((size_t)a * S_ + i) * B_ + b];
    __syncthreads();                        // tg_lds ready

    const size_t s_stride = (size_t)B_ * T_ * T_;         // 65536 floats per step
    const float* cb = scores + ((size_t)a * S_ * B_ + b) * (T_ * T_);

    const int nf = L / 2;                   // forward tiles 1..nf
    const int nb = (L - 1) - nf;            // backward tiles L-1 .. nf+1
    const int nch = (nf + 3) / 4;           // phases (nf >= nb)

    float wcur = 0.0f, C2 = 0.0f, tg0 = 0.0f;
    if (wv == 0) {                          // forward consumer init
        wcur = EXP2F(cb[START_TAG * T_ + t] * LOG2E);
        if (lane < 32) wldsF[lane] = wcur;
        tg0 = cb[tg_lds[0]];                // gold score, step 0
    }
    if (wv == 4) {                          // backward consumer init: G = e_END
        wcur = (t == END_TAG) ? 1.0f : 0.0f;
        if (lane < 32) wldsG[lane] = wcur;
    }
    float tgacc = 0.0f;                     // per-wave gold accumulation

#define E4(DST, SRC) do {                                                \
        DST.x = EXP2F(SRC.x * LOG2E); DST.y = EXP2F(SRC.y * LOG2E);      \
        DST.z = EXP2F(SRC.z * LOG2E); DST.w = EXP2F(SRC.w * LOG2E);      \
    } while (0)

#define RENORMX(WARR) do {                                               \
        float m_ = wcur;                                                 \
        m_ = fmaxf(m_, __shfl_xor(m_, 1));                               \
        m_ = fmaxf(m_, __shfl_xor(m_, 2));                               \
        m_ = fmaxf(m_, __shfl_xor(m_, 4));                               \
        m_ = fmaxf(m_, __shfl_xor(m_, 8));                               \
        m_ = fmaxf(m_, __shfl_xor(m_, 16));                              \
        int eb_ = (__float_as_int(m_) >> 23) & 0xff;                     \
        C2 += (float)(eb_ - 127);                                        \
        float sc2_ = __int_as_float((254 - eb_) << 23);                  \
        wcur *= sc2_;                                                    \
        if (lane < 32) WARR[lane] = wcur;                                \
    } while (0)

    // tile index / validity for this wave at phase KK (wave-uniform)
#define TIDX(KK) ((wv < 4) ? (1 + 4 * (KK) + wv) : (L - 1 - 4 * (KK) - (wv - 4)))
#define TOK(KK)  ((wv < 4) ? (TIDX(KK) <= nf) : (TIDX(KK) >= nf + 1))

#define TLOAD(Q0, Q1, Q2, Q3, GR, KK) do {                               \
        if (TOK(KK)) {                                                   \
            const int s_ = TIDX(KK);                                     \
            const float*  p_  = cb + (size_t)s_ * s_stride;              \
            const float4* p4_ = (const float4*)p_;                       \
            Q0 = p4_[lane];       Q1 = p4_[64 + lane];                   \
            Q2 = p4_[128 + lane]; Q3 = p4_[192 + lane];                  \
            GR = p_[tg_lds[s_]];                                         \
        }                                                                \
    } while (0)

    // PRODUCE: exp + write to slot [KK&1][wv]. Forward: linear float4 (R20).
    // Backward: 16 scalar swizzled writes, word = f*32 + (t ^ f).
#define PRODUCE(Q0, Q1, Q2, Q3, GQ, KK) do {                             \
        if (TOK(KK)) {                                                   \
            float4 e0, e1, e2, e3;                                       \
            E4(e0, Q0); E4(e1, Q1); E4(e2, Q2); E4(e3, Q3);              \
            float* ebw = &ebuf[(KK) & 1][wv][0];                         \
            if (wv < 4) {                                                \
                float4* eb4 = (float4*)ebw;                              \
                eb4[lane] = e0; eb4[64 + lane] = e1;                     \
                eb4[128 + lane] = e2; eb4[192 + lane] = e3;              \
            } else {                                                     \
                const int f0_ = lane >> 3, tb_ = (lane & 7) << 2;        \
                int fx_ = f0_;                                           \
                ebw[fx_ * 32 + ((tb_ + 0) ^ fx_)] = e0.x;                \
                ebw[fx_ * 32 + ((tb_ + 1) ^ fx_)] = e0.y;                \
                ebw[fx_ * 32 + ((tb_ + 2) ^ fx_)] = e0.z;                \
                ebw[fx_ * 32 + ((tb_ + 3) ^ fx_)] = e0.w;                \
                fx_ = f0_ + 8;                                           \
                ebw[fx_ * 32 + ((tb_ + 0) ^ fx_)] = e1.x;                \
                ebw[fx_ * 32 + ((tb_ + 1) ^ fx_)] = e1.y;                \
                ebw[fx_ * 32 + ((tb_ + 2) ^ fx_)] = e1.z;                \
                ebw[fx_ * 32 + ((tb_ + 3) ^ fx_)] = e1.w;                \
                fx_ = f0_ + 16;                                          \
                ebw[fx_ * 32 + ((tb_ + 0) ^ fx_)] = e2.x;                \
                ebw[fx_ * 32 + ((tb_ + 1) ^ fx_)] = e2.y;                \
                ebw[fx_ * 32 + ((tb_ + 2) ^ fx_)] = e2.z;                \
                ebw[fx_ * 32 + ((tb_ + 3) ^ fx_)] = e2.w;                \
                fx_ = f0_ + 24;                                          \
                ebw[fx_ * 32 + ((tb_ + 0) ^ fx_)] = e3.x;                \
                ebw[fx_ * 32 + ((tb_ + 1) ^ fx_)] = e3.y;                \
                ebw[fx_ * 32 + ((tb_ + 2) ^ fx_)] = e3.z;                \
                ebw[fx_ * 32 + ((tb_ + 3) ^ fx_)] = e3.w;                \
            }                                                            \
            tgacc += GQ;                                                 \
        }                                                                \
    } while (0)

    // Forward consumer (wave 0): verbatim R20 step body, slots [kb][0..3].
#define CONSUME_F(KK) do {                                               \
        const int kb_ = (KK) & 1;                                        \
        const int jmax_ = min(4, nf - 4 * (KK));                         \
        for (int j = 0; j < jmax_; ++j) {                                \
            const float* eb = &ebuf[kb_][j][0];                          \
            float4 wa_ = *(const float4*)&wldsF[fbase];                  \
            float4 wb_ = *(const float4*)&wldsF[fbase + 4];              \
            float4 wc_ = *(const float4*)&wldsF[fbase + 8];              \
            float4 wd_ = *(const float4*)&wldsF[fbase + 12];             \
            float e_[16];                                                \
            _Pragma("unroll")                                            \
            for (int i = 0; i < 16; ++i)                                 \
                e_[i] = eb[((fbase + i) << 5) | t];                      \
            float s0_ = fmaf(e_[3], wa_.w, fmaf(e_[2], wa_.z,            \
                        fmaf(e_[1], wa_.y, e_[0] * wa_.x)));             \
            float s1_ = fmaf(e_[7], wb_.w, fmaf(e_[6], wb_.z,            \
                        fmaf(e_[5], wb_.y, e_[4] * wb_.x)));             \
            float s2_ = fmaf(e_[11], wc_.w, fmaf(e_[10], wc_.z,          \
                        fmaf(e_[9], wc_.y, e_[8] * wc_.x)));             \
            float s3_ = fmaf(e_[15], wd_.w, fmaf(e_[14], wd_.z,          \
                        fmaf(e_[13], wd_.y, e_[12] * wd_.x)));           \
            float s_ = (s0_ + s1_) + (s2_ + s3_);                        \
            s_ += __shfl_xor(s_, 32);                                    \
            wcur = s_;                                                   \
            if (lane < 32) wldsF[lane] = s_;                             \
        }                                                                \
        RENORMX(wldsF);                                                  \
    } while (0)

    // Backward consumer (wave 4): G_new[f] = sum_t e[f][t]*G[t]; lane owns
    // f = t(=lane&31); reads swizzled words f*32 + ((fbase+i) ^ f); G via
    // broadcast float4 from wldsG[fbase..]. Slots [kb][4..7], tile order desc.
#define CONSUME_B(KK) do {                                               \
        const int kb_ = (KK) & 1;                                        \
        const int jmax_ = min(4, nb - 4 * (KK));                         \
        for (int j = 0; j < jmax_; ++j) {                                \
            const float* eb = &ebuf[kb_][4 + j][0];                      \
            float4 wa_ = *(const float4*)&wldsG[fbase];                  \
            float4 wb_ = *(const float4*)&wldsG[fbase + 4];              \
            float4 wc_ = *(const float4*)&wldsG[fbase + 8];              \
            float4 wd_ = *(const float4*)&wldsG[fbase + 12];             \
            float e_[16];                                                \
            _Pragma("unroll")                                            \
            for (int i = 0; i < 16; ++i)                                 \
                e_[i] = eb[(t << 5) + ((fbase + i) ^ t)];                \
            float s0_ = fmaf(e_[3], wa_.w, fmaf(e_[2], wa_.z,            \
                        fmaf(e_[1], wa_.y, e_[0] * wa_.x)));             \
            float s1_ = fmaf(e_[7], wb_.w, fmaf(e_[6], wb_.z,            \
                        fmaf(e_[5], wb_.y, e_[4] * wb_.x)));             \
            float s2_ = fmaf(e_[11], wc_.w, fmaf(e_[10], wc_.z,          \
                        fmaf(e_[9], wc_.y, e_[8] * wc_.x)));             \
            float s3_ = fmaf(e_[15], wd_.w, fmaf(e_[14], wd_.z,          \
                        fmaf(e_[13], wd_.y, e_[12] * wd_.x)));           \
            float s_ = (s0_ + s1_) + (s2_ + s3_);                        \
            s_ += __shfl_xor(s_, 32);                                    \
            wcur = s_;                                                   \
            if (lane < 32) wldsG[lane] = s_;                             \
        }                                                                \
        if (jmax_ > 0) RENORMX(wldsG);                                   \
    } while (0)

#define PHASE(Q0, Q1, Q2, Q3, GQ, KK) do {                               \
        const int k_ = (KK);                                             \
        PRODUCE(Q0, Q1, Q2, Q3, GQ, k_);                                 \
        TLOAD(Q0, Q1, Q2, Q3, GQ, k_ + 2);                               \
        LGKM_BARRIER;                                                    \
        if (wv == 0) CONSUME_F(k_);                                      \
        else if (wv == 4) CONSUME_B(k_);                                 \
    } while (0)

    // ---- prologue prefetch: phase 0 -> A, phase 1 -> B ----
    float4 a0, a1, a2, a3, b0, b1, b2, b3;
    float ga = 0.0f, gb = 0.0f;
    TLOAD(a0, a1, a2, a3, ga, 0);
    TLOAD(b0, b1, b2, b3, gb, 1);

    for (int k = 0; k < nch; k += 2) {
        PHASE(a0, a1, a2, a3, ga, k);
        if (k + 1 < nch)
            PHASE(b0, b1, b2, b3, gb, k + 1);
    }

    // ---- handoff: gold sums, backward C2; combine on wave 0 ----
    if (lane == 0) gfin[wv] = tgacc;
    if (wv == 4 && lane == 0) c2b_lds = C2;
    __syncthreads();

    if (wv == 0) {
        float tg = tg0;
#pragma unroll
        for (int w = 0; w < NW; ++w) tg += gfin[w];
        float d = wcur * wldsG[t];          // F[t] * G[t]
        d += __shfl_xor(d, 1);
        d += __shfl_xor(d, 2);
        d += __shfl_xor(d, 4);
        d += __shfl_xor(d, 8);
        d += __shfl_xor(d, 16);
        float logZ = __logf(d) + (C2 + c2b_lds) * LN2;
        if (lane == 0)
            atomicAdd(out, (logZ - tg) * (1.0f / (float)B_));
    }
}

extern "C" void kernel_launch(void* const* d_in, const int* in_sizes, int n_in,
                              void* d_out, int out_size, void* d_ws, size_t ws_size,
                              hipStream_t stream) {
    const float* scores = (const float*)d_in[0];
    const int* targets  = (const int*)d_in[1];
    const void* mask    = d_in[2];
    const void* amask   = d_in[3];
    float* out = (float*)d_out;

    hipMemsetAsync(out, 0, sizeof(float), stream);
    crf_loss_kernel<<<dim3(A_ * B_), dim3(NW * 64), 0, stream>>>(
        scores, targets, mask, amask, out);
}